// Round 1
// baseline (170.254 us; speedup 1.0000x reference)
//
#include <hip/hip_runtime.h>

// out[t,k] = x[t,:] . Mre[k,:]   (T=262144, F=100, K=2)
// Mre[k,a] = sum_ij u[ij]*A_re[k,i,j,a] - v[ij]*A_im[k,i,j,a]
//   u[ij] = pr_i*pr_j + pi_i*pi_j,  v[ij] = pr_i*pi_j - pi_i*pr_j

#define T_ROWS 262144
#define NF 100

__global__ __launch_bounds__(256) void compute_M(
    const float* __restrict__ A_re, const float* __restrict__ A_im,
    const float* __restrict__ psi_re, const float* __restrict__ psi_im,
    float* __restrict__ M)
{
    __shared__ float u[100], v[100];
    int tid = threadIdx.x;
    if (tid < 100) {
        int i = tid / 10, j = tid % 10;
        float pri = psi_re[i], pii = psi_im[i];
        float prj = psi_re[j], pij = psi_im[j];
        u[tid] = pri * prj + pii * pij;   // Re(conj(psi_i) * psi_j)
        v[tid] = pri * pij - pii * prj;   // Im(conj(psi_i) * psi_j)
    }
    __syncthreads();
    if (tid < 200) {
        int k = tid / 100, a = tid % 100;
        const float* Ar = A_re + k * 10000 + a;   // stride 100 over ij
        const float* Ai = A_im + k * 10000 + a;
        float s = 0.f;
#pragma unroll 5
        for (int ij = 0; ij < 100; ++ij) {
            s += u[ij] * Ar[ij * 100] - v[ij] * Ai[ij * 100];
        }
        M[tid] = s;   // M[k*100 + a]
    }
}

// One block = 64 rows. Stage tile into LDS (coalesced float4),
// 4 threads per row, 25 cols each, shfl_xor reduce, float2 store.
__global__ __launch_bounds__(256) void gemv_out(
    const float* __restrict__ x, const float* __restrict__ M,
    float* __restrict__ out)
{
    __shared__ float sx[64 * NF];   // 25600 B
    __shared__ float sM[2 * NF];    // 800 B
    int tid = threadIdx.x;

    if (tid < 200) sM[tid] = M[tid];

    // 64 rows * 100 floats = 6400 floats = 1600 float4
    const float4* xg = (const float4*)(x + (long)blockIdx.x * (64 * NF));
    float4* sx4 = (float4*)sx;
#pragma unroll
    for (int it = 0; it < 6; ++it)
        sx4[tid + it * 256] = xg[tid + it * 256];
    if (tid < 64)
        sx4[tid + 1536] = xg[tid + 1536];
    __syncthreads();

    int r = tid >> 2;        // row within tile, 0..63
    int c = tid & 3;         // column quarter, 0..3
    const float* xr = sx + r * NF + c * 25;
    const float* m0 = sM + c * 25;
    const float* m1 = sM + NF + c * 25;
    float s0 = 0.f, s1 = 0.f;
#pragma unroll
    for (int j = 0; j < 25; ++j) {
        float xv = xr[j];
        s0 += xv * m0[j];
        s1 += xv * m1[j];
    }
    // reduce the 4 column-quarters (lanes r*4+c are contiguous in the wave)
    s0 += __shfl_xor(s0, 1); s1 += __shfl_xor(s1, 1);
    s0 += __shfl_xor(s0, 2); s1 += __shfl_xor(s1, 2);

    if (c == 0) {
        long row = (long)blockIdx.x * 64 + r;
        ((float2*)out)[row] = make_float2(s0, s1);
    }
}

extern "C" void kernel_launch(void* const* d_in, const int* in_sizes, int n_in,
                              void* d_out, int out_size, void* d_ws, size_t ws_size,
                              hipStream_t stream) {
    const float* x      = (const float*)d_in[0];
    const float* A_re   = (const float*)d_in[1];
    const float* A_im   = (const float*)d_in[2];
    const float* psi_re = (const float*)d_in[3];
    const float* psi_im = (const float*)d_in[4];
    float* out = (float*)d_out;
    float* M   = (float*)d_ws;   // 200 floats

    compute_M<<<1, 256, 0, stream>>>(A_re, A_im, psi_re, psi_im, M);
    gemv_out<<<T_ROWS / 64, 256, 0, stream>>>(x, M, out);
}

// Round 2
// 158.808 us; speedup vs baseline: 1.0721x; 1.0721x over previous
//
#include <hip/hip_runtime.h>

// out[t,k] = x[t,:] . Mre[k,:]   (T=262144, F=100, K=2)
// Mre[k,a] = sum_ij u[ij]*A_re[k,i,j,a] - v[ij]*A_im[k,i,j,a]
//   u[ij] = pr_i*pr_j + pi_i*pi_j,  v[ij] = pr_i*pi_j - pi_i*pr_j
//
// Stage 1: 20 blocks, block b=(k*10+slice) sums ij in [slice*10, slice*10+10)
//          -> partial P[b*100 + a] in d_ws (fully written, no memset needed).
// Stage 2: gemv folds the 10 partials per (k,a) into LDS sM, then tiled GEMV.

#define T_ROWS 262144
#define NF 100

__global__ __launch_bounds__(256) void compute_M_partial(
    const float* __restrict__ A_re, const float* __restrict__ A_im,
    const float* __restrict__ psi_re, const float* __restrict__ psi_im,
    float* __restrict__ P)
{
    __shared__ float u[100], v[100];
    __shared__ float sp[256];
    int t = threadIdx.x;
    int b = blockIdx.x;          // 0..19
    int k = b / 10;              // class
    int slice = b % 10;          // ij decade

    if (t < 100) {
        int i = t / 10, j = t % 10;
        float pri = psi_re[i], pii = psi_im[i];
        float prj = psi_re[j], pij = psi_im[j];
        u[t] = pri * prj + pii * pij;   // Re(conj(psi_i) * psi_j)
        v[t] = pri * pij - pii * prj;   // Im(conj(psi_i) * psi_j)
    }
    __syncthreads();

    float s = 0.f;
    if (t < 200) {
        int ij_off = t / 100;    // 0 or 1
        int a = t % 100;
        const float* Ar = A_re + k * 10000;
        const float* Ai = A_im + k * 10000;
#pragma unroll
        for (int m = 0; m < 5; ++m) {
            int ij = slice * 10 + ij_off + 2 * m;
            // consecutive t -> consecutive a -> coalesced
            s += u[ij] * Ar[ij * 100 + a] - v[ij] * Ai[ij * 100 + a];
        }
    }
    sp[t] = s;
    __syncthreads();
    if (t < 100) {
        P[b * 100 + t] = sp[t] + sp[t + 100];
    }
}

// One block = 64 rows. Stage tile into LDS (coalesced float4),
// 4 threads per row, 25 cols each, shfl_xor reduce, float2 store.
__global__ __launch_bounds__(256) void gemv_out(
    const float* __restrict__ x, const float* __restrict__ P,
    float* __restrict__ out)
{
    __shared__ float sx[64 * NF];   // 25600 B
    __shared__ float sM[2 * NF];    // 800 B
    int tid = threadIdx.x;

    // Fold the 10 ij-decade partials: sM[k*100+a] = sum_s P[k*1000 + s*100 + a]
    if (tid < 200) {
        int k = tid / 100, a = tid % 100;
        float m = 0.f;
#pragma unroll
        for (int s = 0; s < 10; ++s)
            m += P[k * 1000 + s * 100 + a];
        sM[tid] = m;
    }

    // 64 rows * 100 floats = 6400 floats = 1600 float4
    const float4* xg = (const float4*)(x + (long)blockIdx.x * (64 * NF));
    float4* sx4 = (float4*)sx;
#pragma unroll
    for (int it = 0; it < 6; ++it)
        sx4[tid + it * 256] = xg[tid + it * 256];
    if (tid < 64)
        sx4[tid + 1536] = xg[tid + 1536];
    __syncthreads();

    int r = tid >> 2;        // row within tile, 0..63
    int c = tid & 3;         // column quarter, 0..3
    const float* xr = sx + r * NF + c * 25;
    const float* m0 = sM + c * 25;
    const float* m1 = sM + NF + c * 25;
    float s0 = 0.f, s1 = 0.f;
#pragma unroll
    for (int j = 0; j < 25; ++j) {
        float xv = xr[j];
        s0 += xv * m0[j];
        s1 += xv * m1[j];
    }
    // reduce the 4 column-quarters (lanes r*4+c are contiguous in the wave)
    s0 += __shfl_xor(s0, 1); s1 += __shfl_xor(s1, 1);
    s0 += __shfl_xor(s0, 2); s1 += __shfl_xor(s1, 2);

    if (c == 0) {
        long row = (long)blockIdx.x * 64 + r;
        ((float2*)out)[row] = make_float2(s0, s1);
    }
}

extern "C" void kernel_launch(void* const* d_in, const int* in_sizes, int n_in,
                              void* d_out, int out_size, void* d_ws, size_t ws_size,
                              hipStream_t stream) {
    const float* x      = (const float*)d_in[0];
    const float* A_re   = (const float*)d_in[1];
    const float* A_im   = (const float*)d_in[2];
    const float* psi_re = (const float*)d_in[3];
    const float* psi_im = (const float*)d_in[4];
    float* out = (float*)d_out;
    float* P   = (float*)d_ws;   // 20*100 floats of partials

    compute_M_partial<<<20, 256, 0, stream>>>(A_re, A_im, psi_re, psi_im, P);
    gemv_out<<<T_ROWS / 64, 256, 0, stream>>>(x, P, out);
}